// Round 2
// baseline (4337.438 us; speedup 1.0000x reference)
//
#include <hip/hip_runtime.h>
#include <hip/hip_bf16.h>
#include <cstdint>
#include <cstddef>

#define B_ 128
#define I_ 512
#define T_ 256
#define H_ 1024

typedef __attribute__((ext_vector_type(8))) short short8;
typedef __attribute__((ext_vector_type(4))) float floatx4;

static __device__ __forceinline__ unsigned short f2bf(float f) {
  unsigned u = __float_as_uint(f);
  u += 0x7FFFu + ((u >> 16) & 1u);   // RNE
  return (unsigned short)(u >> 16);
}
static __device__ __forceinline__ short8 pack_bf8(floatx4 a, floatx4 b) {
  short8 v;
  v[0] = (short)f2bf(a[0]); v[1] = (short)f2bf(a[1]);
  v[2] = (short)f2bf(a[2]); v[3] = (short)f2bf(a[3]);
  v[4] = (short)f2bf(b[0]); v[5] = (short)f2bf(b[1]);
  v[6] = (short)f2bf(b[2]); v[7] = (short)f2bf(b[3]);
  return v;
}

// ---------------------------------------------------------------------------
// Kernel 1: x [B][I][T] fp32  ->  xs [(t*B+b)][I] bf16   (transpose + cast)
// ---------------------------------------------------------------------------
__global__ void __launch_bounds__(256) k_transpose(
    const float* __restrict__ x, unsigned short* __restrict__ xs) {
  __shared__ float tile[64][65];                 // +1 pad: conflict-free both ways
  const int b  = blockIdx.x;
  const int i0 = blockIdx.y * 64;
  const int t0 = blockIdx.z * 64;
  const int tid = threadIdx.x;
  const int c = tid & 63, r4 = tid >> 6;         // 64 cols, 4 rows per iter
  const float* src = x + (size_t)b * I_ * T_ + (size_t)i0 * T_ + t0;
#pragma unroll
  for (int it = 0; it < 16; ++it) {
    const int r = it * 4 + r4;
    tile[r][c] = src[(size_t)r * T_ + c];        // coalesced along t
  }
  __syncthreads();
#pragma unroll
  for (int it = 0; it < 16; ++it) {
    const int tr = it * 4 + r4;
    xs[((size_t)(t0 + tr) * B_ + b) * I_ + i0 + c] = f2bf(tile[c][tr]); // coalesced along i
  }
}

// ---------------------------------------------------------------------------
// Kernel 2: persistent recurrent kernel, fused input projection.
// 256 WGs x 256 thr, grid == CU count -> co-resident by construction.
// WG(bt,jt): batch tile bt (32 rows) x 16 h-units (x4 gates = 64 gate cols).
// Per step: gates = [x_t | h] @ [W_ih | W_hh]^T + bias, K = 512 + 1024.
// Weights live in 192 VGPRs/lane; c in 2 regs/thread; h round-trips global
// bf16 double-buffered; flag barrier over the 64-WG batch group only.
// ---------------------------------------------------------------------------
__global__ void __launch_bounds__(256, 1) k_lstm(
    const unsigned short* __restrict__ xs,    // [T*B][512] bf16
    const float* __restrict__ Whh,            // [4096][1024] fp32
    const float* __restrict__ Wih,            // [4096][512]  fp32
    const float* __restrict__ bih,            // [4096]
    const float* __restrict__ bhh,            // [4096]
    unsigned short* __restrict__ h0buf,       // [128][1024] bf16 (zeroed)
    unsigned short* __restrict__ h1buf,
    float* __restrict__ out,                  // [128][1024] fp32
    unsigned int* __restrict__ flags)         // [256] zeroed
{
  __shared__ unsigned short hst[2][32][264];  // K-chunk staging (pitch 264)
  __shared__ float gx[4][32][17];             // gate exchange i/f/g/o

  const int wg = blockIdx.x, tid = threadIdx.x;
  const int lane = tid & 63, wave = tid >> 6; // wave == gate index q
  const int bt = wg & 3, jt = wg >> 2;
  const int b0 = bt * 32, j0 = jt * 16;
  const int quad = lane >> 4, cr = lane & 15;

  // ---- preload weight B-fragments (static across all timesteps) ----
  short8 whf[32];                             // W_hh: K=1024 -> 32 k-steps
  {
    const float* wrow = Whh + (size_t)(wave * H_ + j0 + cr) * H_;
#pragma unroll
    for (int ks = 0; ks < 32; ++ks) {
      floatx4 wa = *(const floatx4*)(wrow + ks * 32 + quad * 8);
      floatx4 wb = *(const floatx4*)(wrow + ks * 32 + quad * 8 + 4);
      whf[ks] = pack_bf8(wa, wb);
    }
  }
  short8 wif[16];                             // W_ih: K=512 -> 16 k-steps
  {
    const float* irow = Wih + (size_t)(wave * H_ + j0 + cr) * I_;
#pragma unroll
    for (int ks = 0; ks < 16; ++ks) {
      floatx4 wa = *(const floatx4*)(irow + ks * 32 + quad * 8);
      floatx4 wb = *(const floatx4*)(irow + ks * 32 + quad * 8 + 4);
      wif[ks] = pack_bf8(wa, wb);
    }
  }

  const int eb = tid >> 3;    // epilogue batch row (0..31)
  const int ejp = tid & 7;    // epilogue j-pair   (0..7)
  float bias[4][2];
#pragma unroll
  for (int q = 0; q < 4; ++q)
#pragma unroll
    for (int jj = 0; jj < 2; ++jj)
      bias[q][jj] = bih[q * H_ + j0 + ejp * 2 + jj] + bhh[q * H_ + j0 + ejp * 2 + jj];

  const int srow = tid >> 3;  // staging row (0..31)
  const int sq = tid & 7;     // staging col octet
  const int flagIdx = bt + 4 * lane;  // the 64 WGs of this batch group

  float c0 = 0.f, c1 = 0.f;

  for (int t = 0; t < T_; ++t) {
    const unsigned short* hin = (t & 1) ? h1buf : h0buf;
    unsigned short* hout      = (t & 1) ? h0buf : h1buf;
    const unsigned short* xrow = xs + ((size_t)t * B_ + b0 + srow) * I_ + sq * 8;
    const unsigned short* hrow = hin + (size_t)(b0 + srow) * H_ + sq * 8;

    // ---- stage x chunk 0 (no dependence on h -> runs before barrier) ----
    {
      short8 s0 = *(const short8*)(xrow + 0);
      short8 s1 = *(const short8*)(xrow + 64);
      short8 s2 = *(const short8*)(xrow + 128);
      short8 s3 = *(const short8*)(xrow + 192);
      *(short8*)&hst[0][srow][sq * 8 + 0]   = s0;
      *(short8*)&hst[0][srow][sq * 8 + 64]  = s1;
      *(short8*)&hst[0][srow][sq * 8 + 128] = s2;
      *(short8*)&hst[0][srow][sq * 8 + 192] = s3;
    }
    __syncthreads();

    floatx4 acc0 = {0.f, 0.f, 0.f, 0.f};
    floatx4 acc1 = {0.f, 0.f, 0.f, 0.f};

    // ---- x chunk 0 MFMA + prefetch x chunk 1 ----
    {
      short8 p0 = *(const short8*)(xrow + 256 + 0);
      short8 p1 = *(const short8*)(xrow + 256 + 64);
      short8 p2 = *(const short8*)(xrow + 256 + 128);
      short8 p3 = *(const short8*)(xrow + 256 + 192);
#pragma unroll
      for (int ks8 = 0; ks8 < 8; ++ks8) {
        short8 a0 = *(const short8*)&hst[0][cr][ks8 * 32 + quad * 8];
        short8 a1 = *(const short8*)&hst[0][16 + cr][ks8 * 32 + quad * 8];
        acc0 = __builtin_amdgcn_mfma_f32_16x16x32_bf16(a0, wif[ks8], acc0, 0, 0, 0);
        acc1 = __builtin_amdgcn_mfma_f32_16x16x32_bf16(a1, wif[ks8], acc1, 0, 0, 0);
      }
      *(short8*)&hst[1][srow][sq * 8 + 0]   = p0;
      *(short8*)&hst[1][srow][sq * 8 + 64]  = p1;
      *(short8*)&hst[1][srow][sq * 8 + 128] = p2;
      *(short8*)&hst[1][srow][sq * 8 + 192] = p3;
    }
    __syncthreads();

    // ---- wait until all WGs of this batch group published h(t) ----
    if (t > 0) {
      const unsigned tgt = (unsigned)t;
      while (__hip_atomic_load(&flags[flagIdx], __ATOMIC_RELAXED,
                               __HIP_MEMORY_SCOPE_AGENT) < tgt)
        __builtin_amdgcn_s_sleep(1);
      __builtin_amdgcn_fence(__ATOMIC_ACQUIRE, "agent");
    }

    // ---- x chunk 1 MFMA + prefetch h chunk 0 ----
    {
      short8 p0 = *(const short8*)(hrow + 0);
      short8 p1 = *(const short8*)(hrow + 64);
      short8 p2 = *(const short8*)(hrow + 128);
      short8 p3 = *(const short8*)(hrow + 192);
#pragma unroll
      for (int ks8 = 0; ks8 < 8; ++ks8) {
        short8 a0 = *(const short8*)&hst[1][cr][ks8 * 32 + quad * 8];
        short8 a1 = *(const short8*)&hst[1][16 + cr][ks8 * 32 + quad * 8];
        acc0 = __builtin_amdgcn_mfma_f32_16x16x32_bf16(a0, wif[8 + ks8], acc0, 0, 0, 0);
        acc1 = __builtin_amdgcn_mfma_f32_16x16x32_bf16(a1, wif[8 + ks8], acc1, 0, 0, 0);
      }
      *(short8*)&hst[0][srow][sq * 8 + 0]   = p0;
      *(short8*)&hst[0][srow][sq * 8 + 64]  = p1;
      *(short8*)&hst[0][srow][sq * 8 + 128] = p2;
      *(short8*)&hst[0][srow][sq * 8 + 192] = p3;
    }
    __syncthreads();

    // ---- h chunks 0..3 (K = 1024), double-buffered ----
#pragma unroll
    for (int ch = 0; ch < 4; ++ch) {
      short8 p0, p1, p2, p3;
      if (ch < 3) {
        const unsigned short* src = hrow + (ch + 1) * 256;
        p0 = *(const short8*)(src + 0);
        p1 = *(const short8*)(src + 64);
        p2 = *(const short8*)(src + 128);
        p3 = *(const short8*)(src + 192);
      }
#pragma unroll
      for (int ks8 = 0; ks8 < 8; ++ks8) {
        short8 a0 = *(const short8*)&hst[ch & 1][cr][ks8 * 32 + quad * 8];
        short8 a1 = *(const short8*)&hst[ch & 1][16 + cr][ks8 * 32 + quad * 8];
        acc0 = __builtin_amdgcn_mfma_f32_16x16x32_bf16(a0, whf[ch * 8 + ks8], acc0, 0, 0, 0);
        acc1 = __builtin_amdgcn_mfma_f32_16x16x32_bf16(a1, whf[ch * 8 + ks8], acc1, 0, 0, 0);
      }
      if (ch < 3) {
        *(short8*)&hst[(ch + 1) & 1][srow][sq * 8 + 0]   = p0;
        *(short8*)&hst[(ch + 1) & 1][srow][sq * 8 + 64]  = p1;
        *(short8*)&hst[(ch + 1) & 1][srow][sq * 8 + 128] = p2;
        *(short8*)&hst[(ch + 1) & 1][srow][sq * 8 + 192] = p3;
        __syncthreads();
      }
    }

    // ---- cross-wave gate exchange: wave q holds gate q of a 32b x 16j tile
#pragma unroll
    for (int r = 0; r < 4; ++r) {
      gx[wave][quad * 4 + r][cr]      = acc0[r];  // C/D: row=quad*4+r, col=cr
      gx[wave][16 + quad * 4 + r][cr] = acc1[r];
    }
    __syncthreads();

    // ---- epilogue: activations, c update, h write ----
    float hv0 = 0.f, hv1 = 0.f;
#pragma unroll
    for (int jj = 0; jj < 2; ++jj) {
      const int j = ejp * 2 + jj;
      float gi = gx[0][eb][j] + bias[0][jj];
      float gf = gx[1][eb][j] + bias[1][jj];
      float gg = gx[2][eb][j] + bias[2][jj];
      float go = gx[3][eb][j] + bias[3][jj];
      float si = 1.f / (1.f + __expf(-gi));
      float sf = 1.f / (1.f + __expf(-gf));
      float tg = 2.f / (1.f + __expf(-2.f * gg)) - 1.f;   // tanh
      float so = 1.f / (1.f + __expf(-go));
      float& cc = jj ? c1 : c0;
      cc = sf * cc + si * tg;
      float th = 2.f / (1.f + __expf(-2.f * cc)) - 1.f;
      float hv = so * th;
      if (jj == 0) hv0 = hv; else hv1 = hv;
    }
    const unsigned hpack = (unsigned)f2bf(hv0) | ((unsigned)f2bf(hv1) << 16);
    *(unsigned*)(hout + (size_t)(b0 + eb) * H_ + j0 + ejp * 2) = hpack;
    if (t == T_ - 1) {
      out[(size_t)(b0 + eb) * H_ + j0 + ejp * 2 + 0] = hv0;
      out[(size_t)(b0 + eb) * H_ + j0 + ejp * 2 + 1] = hv1;
    }

    // ---- publish h(t+1): syncthreads drains vmcnt -> stores are in L2 ----
    __syncthreads();
    if (tid == 0) {
      __builtin_amdgcn_fence(__ATOMIC_RELEASE, "agent");
      __hip_atomic_store(&flags[wg], (unsigned)(t + 1),
                         __ATOMIC_RELAXED, __HIP_MEMORY_SCOPE_AGENT);
    }
  }
}

// ---------------------------------------------------------------------------
extern "C" void kernel_launch(void* const* d_in, const int* in_sizes, int n_in,
                              void* d_out, int out_size, void* d_ws, size_t ws_size,
                              hipStream_t stream) {
  (void)in_sizes; (void)n_in; (void)out_size; (void)ws_size;
  const float* x   = (const float*)d_in[0];
  const float* Wih = (const float*)d_in[1];
  const float* Whh = (const float*)d_in[2];
  const float* bih = (const float*)d_in[3];
  const float* bhh = (const float*)d_in[4];
  float* out = (float*)d_out;

  // workspace layout (total ~34.1 MB)
  char* ws = (char*)d_ws;
  unsigned short* xs = (unsigned short*)ws;                       // 33,554,432 B
  unsigned short* h0 = (unsigned short*)(ws + 33554432);          //    262,144 B
  unsigned short* h1 = (unsigned short*)(ws + 33816576);          //    262,144 B
  unsigned int*   fl = (unsigned int*)  (ws + 34078720);          //      1,024 B

  // ws is poisoned 0xAA before every timed call: re-init state we rely on.
  hipMemsetAsync(h0, 0, 262144, stream);
  hipMemsetAsync(fl, 0, 1024, stream);

  k_transpose<<<dim3(B_, I_ / 64, T_ / 64), 256, 0, stream>>>(x, xs);

  // Plain launch: grid == 256 CUs, 1 WG/CU -> co-resident by construction.
  k_lstm<<<dim3(256), dim3(256), 0, stream>>>(xs, Whh, Wih, bih, bhh,
                                              h0, h1, out, fl);
}

// Round 3
// 1994.701 us; speedup vs baseline: 2.1745x; 2.1745x over previous
//
#include <hip/hip_runtime.h>
#include <hip/hip_bf16.h>
#include <cstdint>
#include <cstddef>

#define B_ 128
#define I_ 512
#define T_ 256
#define H_ 1024

typedef __attribute__((ext_vector_type(8))) short short8;
typedef __attribute__((ext_vector_type(4))) float floatx4;

static __device__ __forceinline__ unsigned short f2bf(float f) {
  unsigned u = __float_as_uint(f);
  u += 0x7FFFu + ((u >> 16) & 1u);   // RNE
  return (unsigned short)(u >> 16);
}
static __device__ __forceinline__ short8 pack_bf8(floatx4 a, floatx4 b) {
  short8 v;
  v[0] = (short)f2bf(a[0]); v[1] = (short)f2bf(a[1]);
  v[2] = (short)f2bf(a[2]); v[3] = (short)f2bf(a[3]);
  v[4] = (short)f2bf(b[0]); v[5] = (short)f2bf(b[1]);
  v[6] = (short)f2bf(b[2]); v[7] = (short)f2bf(b[3]);
  return v;
}

// ---------------------------------------------------------------------------
// Kernel 1: x [B][I][T] fp32  ->  xs [(t*B+b)][I] bf16   (transpose + cast)
// ---------------------------------------------------------------------------
__global__ void __launch_bounds__(256) k_transpose(
    const float* __restrict__ x, unsigned short* __restrict__ xs) {
  __shared__ float tile[64][65];
  const int b  = blockIdx.x;
  const int i0 = blockIdx.y * 64;
  const int t0 = blockIdx.z * 64;
  const int tid = threadIdx.x;
  const int c = tid & 63, r4 = tid >> 6;
  const float* src = x + (size_t)b * I_ * T_ + (size_t)i0 * T_ + t0;
#pragma unroll
  for (int it = 0; it < 16; ++it) {
    const int r = it * 4 + r4;
    tile[r][c] = src[(size_t)r * T_ + c];
  }
  __syncthreads();
#pragma unroll
  for (int it = 0; it < 16; ++it) {
    const int tr = it * 4 + r4;
    xs[((size_t)(t0 + tr) * B_ + b) * I_ + i0 + c] = f2bf(tile[c][tr]);
  }
}

// ---------------------------------------------------------------------------
// Kernel 2: persistent LSTM. 256 WGs x 256 thr (1 WG/CU, co-resident).
// WG(bt,jt): 32 batch rows x 16 h-units (x4 gates). K = 512(x) + 1024(h).
// Cross-XCD h exchange via IF$ point-to-point: agent-scope atomic stores
// (write-through) + agent-scope atomic loads (L1/L2 bypass). NO cache-walk
// fences (buffer_wbl2/inv were 15us/step in R2).
// ---------------------------------------------------------------------------
__global__ void __launch_bounds__(256, 1) k_lstm(
    const unsigned short* __restrict__ xs,    // [T*B][512] bf16
    const float* __restrict__ Whh,            // [4096][1024] fp32
    const float* __restrict__ Wih,            // [4096][512]  fp32
    const float* __restrict__ bih,            // [4096]
    const float* __restrict__ bhh,            // [4096]
    unsigned short* __restrict__ h0buf,       // [128][1024] bf16
    unsigned short* __restrict__ h1buf,
    float* __restrict__ out,                  // [128][1024] fp32
    unsigned int* __restrict__ flags)         // [T*4] zeroed
{
  __shared__ unsigned short hst[2][32][264];  // staging, pitch 264 (528B)
  __shared__ float gx[4][32][17];             // gate exchange i/f/g/o

  const int wg = blockIdx.x, tid = threadIdx.x;
  const int lane = tid & 63, wave = tid >> 6; // wave == gate index q
  const int bt = wg & 3, jt = wg >> 2;        // jt in [0,64)
  const int b0 = bt * 32, j0 = jt * 16;
  const int quad = lane >> 4, cr = lane & 15;

  // ---- preload weight B-fragments (static across all timesteps) ----
  short8 whf[32];                             // W_hh: K=1024
  {
    const float* wrow = Whh + (size_t)(wave * H_ + j0 + cr) * H_;
#pragma unroll
    for (int ks = 0; ks < 32; ++ks) {
      floatx4 wa = *(const floatx4*)(wrow + ks * 32 + quad * 8);
      floatx4 wb = *(const floatx4*)(wrow + ks * 32 + quad * 8 + 4);
      whf[ks] = pack_bf8(wa, wb);
    }
  }
  short8 wif[16];                             // W_ih: K=512
  {
    const float* irow = Wih + (size_t)(wave * H_ + j0 + cr) * I_;
#pragma unroll
    for (int ks = 0; ks < 16; ++ks) {
      floatx4 wa = *(const floatx4*)(irow + ks * 32 + quad * 8);
      floatx4 wb = *(const floatx4*)(irow + ks * 32 + quad * 8 + 4);
      wif[ks] = pack_bf8(wa, wb);
    }
  }

  const int eb = tid >> 3;    // epilogue batch row (0..31)
  const int ejp = tid & 7;    // epilogue j-pair   (0..7)
  float bias[4][2];
#pragma unroll
  for (int q = 0; q < 4; ++q)
#pragma unroll
    for (int jj = 0; jj < 2; ++jj)
      bias[q][jj] = bih[q * H_ + j0 + ejp * 2 + jj] + bhh[q * H_ + j0 + ejp * 2 + jj];

  const int srow = tid >> 3;  // staging row (0..31)
  const int sq = tid & 7;     // staging col octet

  float c0 = 0.f, c1 = 0.f;

  for (int t = 0; t < T_; ++t) {
    unsigned short* hin  = (t & 1) ? h1buf : h0buf;
    unsigned short* hout = (t & 1) ? h0buf : h1buf;
    const unsigned short* xrow = xs + ((size_t)t * B_ + b0 + srow) * I_ + sq * 8;
    const unsigned short* hrow = hin + (size_t)(b0 + srow) * H_ + sq * 8;

    // ---- x phase (no h dependence) ----
    {
      short8 s0 = *(const short8*)(xrow + 0);
      short8 s1 = *(const short8*)(xrow + 64);
      short8 s2 = *(const short8*)(xrow + 128);
      short8 s3 = *(const short8*)(xrow + 192);
      *(short8*)&hst[0][srow][sq * 8 + 0]   = s0;
      *(short8*)&hst[0][srow][sq * 8 + 64]  = s1;
      *(short8*)&hst[0][srow][sq * 8 + 128] = s2;
      *(short8*)&hst[0][srow][sq * 8 + 192] = s3;
    }
    __syncthreads();                                   // bar 1: x0 visible

    floatx4 accx0 = {0.f, 0.f, 0.f, 0.f};
    floatx4 accx1 = {0.f, 0.f, 0.f, 0.f};
    floatx4 acch0 = {0.f, 0.f, 0.f, 0.f};
    floatx4 acch1 = {0.f, 0.f, 0.f, 0.f};

    {
      short8 p0 = *(const short8*)(xrow + 256 + 0);
      short8 p1 = *(const short8*)(xrow + 256 + 64);
      short8 p2 = *(const short8*)(xrow + 256 + 128);
      short8 p3 = *(const short8*)(xrow + 256 + 192);
#pragma unroll
      for (int ks8 = 0; ks8 < 8; ++ks8) {
        short8 a0 = *(const short8*)&hst[0][cr][ks8 * 32 + quad * 8];
        short8 a1 = *(const short8*)&hst[0][16 + cr][ks8 * 32 + quad * 8];
        accx0 = __builtin_amdgcn_mfma_f32_16x16x32_bf16(a0, wif[ks8], accx0, 0, 0, 0);
        accx1 = __builtin_amdgcn_mfma_f32_16x16x32_bf16(a1, wif[ks8], accx1, 0, 0, 0);
      }
      *(short8*)&hst[1][srow][sq * 8 + 0]   = p0;
      *(short8*)&hst[1][srow][sq * 8 + 64]  = p1;
      *(short8*)&hst[1][srow][sq * 8 + 128] = p2;
      *(short8*)&hst[1][srow][sq * 8 + 192] = p3;
    }

    // ---- wait for h(t): poll per-(step,group) arrival counter (tid0 only) ----
    if (t > 0 && tid == 0) {
      while (__hip_atomic_load(&flags[(t - 1) * 4 + bt], __ATOMIC_RELAXED,
                               __HIP_MEMORY_SCOPE_AGENT) != 64u)
        __builtin_amdgcn_s_sleep(1);
    }
    __syncthreads();                                   // bar 2: x1 visible + flag passed

    if (t > 0) {
      // ---- issue ALL h loads (L1/L2-bypassing, served by IF$) upfront ----
      unsigned long long hv[32];
#pragma unroll
      for (int k = 0; k < 32; ++k) {
        const int c = k >> 3, part = (k >> 1) & 3, half = k & 1;
        hv[k] = __hip_atomic_load(
            (const unsigned long long*)(hrow + c * 256 + part * 64 + half * 4),
            __ATOMIC_RELAXED, __HIP_MEMORY_SCOPE_AGENT);
      }

      // MFMA x chunk 1 (overlaps h-load latency)
#pragma unroll
      for (int ks8 = 0; ks8 < 8; ++ks8) {
        short8 a0 = *(const short8*)&hst[1][cr][ks8 * 32 + quad * 8];
        short8 a1 = *(const short8*)&hst[1][16 + cr][ks8 * 32 + quad * 8];
        accx0 = __builtin_amdgcn_mfma_f32_16x16x32_bf16(a0, wif[8 + ks8], accx0, 0, 0, 0);
        accx1 = __builtin_amdgcn_mfma_f32_16x16x32_bf16(a1, wif[8 + ks8], accx1, 0, 0, 0);
      }

      // stage h chunk 0
#pragma unroll
      for (int p = 0; p < 8; ++p)
        *(unsigned long long*)&hst[0][srow][sq * 8 + (p >> 1) * 64 + (p & 1) * 4] = hv[p];
      __syncthreads();                                 // bar 3

      // h chunks with alternating buffers
#pragma unroll
      for (int ch = 0; ch < 4; ++ch) {
#pragma unroll
        for (int ks8 = 0; ks8 < 8; ++ks8) {
          short8 a0 = *(const short8*)&hst[ch & 1][cr][ks8 * 32 + quad * 8];
          short8 a1 = *(const short8*)&hst[ch & 1][16 + cr][ks8 * 32 + quad * 8];
          acch0 = __builtin_amdgcn_mfma_f32_16x16x32_bf16(a0, whf[ch * 8 + ks8], acch0, 0, 0, 0);
          acch1 = __builtin_amdgcn_mfma_f32_16x16x32_bf16(a1, whf[ch * 8 + ks8], acch1, 0, 0, 0);
        }
        if (ch < 3) {
#pragma unroll
          for (int p = 0; p < 8; ++p)
            *(unsigned long long*)&hst[(ch + 1) & 1][srow]
                [sq * 8 + (p >> 1) * 64 + (p & 1) * 4] = hv[(ch + 1) * 8 + p];
          __syncthreads();                             // bars 4,5,6
        }
      }
    } else {
      // t == 0: h is zero, only x chunk 1 contributes
#pragma unroll
      for (int ks8 = 0; ks8 < 8; ++ks8) {
        short8 a0 = *(const short8*)&hst[1][cr][ks8 * 32 + quad * 8];
        short8 a1 = *(const short8*)&hst[1][16 + cr][ks8 * 32 + quad * 8];
        accx0 = __builtin_amdgcn_mfma_f32_16x16x32_bf16(a0, wif[8 + ks8], accx0, 0, 0, 0);
        accx1 = __builtin_amdgcn_mfma_f32_16x16x32_bf16(a1, wif[8 + ks8], accx1, 0, 0, 0);
      }
    }

    // ---- cross-wave gate exchange ----
    __syncthreads();                                   // bar 7a: LDS reads of hst done
#pragma unroll
    for (int r = 0; r < 4; ++r) {
      gx[wave][quad * 4 + r][cr]      = accx0[r] + acch0[r];
      gx[wave][16 + quad * 4 + r][cr] = accx1[r] + acch1[r];
    }
    __syncthreads();                                   // bar 7b: gx visible

    // ---- epilogue: activations, c update, h publish ----
    float hv0 = 0.f, hv1 = 0.f;
#pragma unroll
    for (int jj = 0; jj < 2; ++jj) {
      const int j = ejp * 2 + jj;
      float gi = gx[0][eb][j] + bias[0][jj];
      float gf = gx[1][eb][j] + bias[1][jj];
      float gg = gx[2][eb][j] + bias[2][jj];
      float go = gx[3][eb][j] + bias[3][jj];
      float si = 1.f / (1.f + __expf(-gi));
      float sf = 1.f / (1.f + __expf(-gf));
      float tg = 2.f / (1.f + __expf(-2.f * gg)) - 1.f;
      float so = 1.f / (1.f + __expf(-go));
      float& cc = jj ? c1 : c0;
      cc = sf * cc + si * tg;
      float th = 2.f / (1.f + __expf(-2.f * cc)) - 1.f;
      float hv = so * th;
      if (jj == 0) hv0 = hv; else hv1 = hv;
    }
    const unsigned hpack = (unsigned)f2bf(hv0) | ((unsigned)f2bf(hv1) << 16);
    // write-through to IF$ (coherence point) — no wbl2 fence needed
    __hip_atomic_store((unsigned*)(hout + (size_t)(b0 + eb) * H_ + j0 + ejp * 2),
                       hpack, __ATOMIC_RELAXED, __HIP_MEMORY_SCOPE_AGENT);
    if (t == T_ - 1) {
      out[(size_t)(b0 + eb) * H_ + j0 + ejp * 2 + 0] = hv0;
      out[(size_t)(b0 + eb) * H_ + j0 + ejp * 2 + 1] = hv1;
    }

    // ---- publish: bar drains vmcnt(0) (h stores acked at IF$), then count ----
    __syncthreads();                                   // bar 8
    if (tid == 0)
      __hip_atomic_fetch_add(&flags[t * 4 + bt], 1u, __ATOMIC_RELAXED,
                             __HIP_MEMORY_SCOPE_AGENT);
  }
}

// ---------------------------------------------------------------------------
extern "C" void kernel_launch(void* const* d_in, const int* in_sizes, int n_in,
                              void* d_out, int out_size, void* d_ws, size_t ws_size,
                              hipStream_t stream) {
  (void)in_sizes; (void)n_in; (void)out_size; (void)ws_size;
  const float* x   = (const float*)d_in[0];
  const float* Wih = (const float*)d_in[1];
  const float* Whh = (const float*)d_in[2];
  const float* bih = (const float*)d_in[3];
  const float* bhh = (const float*)d_in[4];
  float* out = (float*)d_out;

  // workspace layout (total ~34.1 MB — same budget that passed in R2)
  char* ws = (char*)d_ws;
  unsigned short* xs = (unsigned short*)ws;                       // 33,554,432 B
  unsigned short* h0 = (unsigned short*)(ws + 33554432);          //    262,144 B
  unsigned short* h1 = (unsigned short*)(ws + 33816576);          //    262,144 B
  unsigned int*   fl = (unsigned int*)  (ws + 34078720);          //      4,096 B

  // flags are arrival counters per (step, batch-group): must start at 0.
  // (h buffers need no init: t=0 skips the h-GEMM entirely.)
  hipMemsetAsync(fl, 0, 4096, stream);

  k_transpose<<<dim3(B_, I_ / 64, T_ / 64), 256, 0, stream>>>(x, xs);

  k_lstm<<<dim3(256), dim3(256), 0, stream>>>(xs, Whh, Wih, bih, bhh,
                                              h0, h1, out, fl);
}

// Round 4
// 1404.972 us; speedup vs baseline: 3.0872x; 1.4197x over previous
//
#include <hip/hip_runtime.h>
#include <hip/hip_bf16.h>
#include <cstdint>
#include <cstddef>

#define B_ 128
#define I_ 512
#define T_ 256
#define H_ 1024

typedef __attribute__((ext_vector_type(8))) short short8;
typedef __attribute__((ext_vector_type(4))) float floatx4;

static __device__ __forceinline__ unsigned short f2bf(float f) {
  unsigned u = __float_as_uint(f);
  u += 0x7FFFu + ((u >> 16) & 1u);   // RNE
  return (unsigned short)(u >> 16);
}
static __device__ __forceinline__ short8 pack_bf8(floatx4 a, floatx4 b) {
  short8 v;
  v[0] = (short)f2bf(a[0]); v[1] = (short)f2bf(a[1]);
  v[2] = (short)f2bf(a[2]); v[3] = (short)f2bf(a[3]);
  v[4] = (short)f2bf(b[0]); v[5] = (short)f2bf(b[1]);
  v[6] = (short)f2bf(b[2]); v[7] = (short)f2bf(b[3]);
  return v;
}

// ---------------------------------------------------------------------------
// Kernel 1: x [B][I][T] fp32  ->  xs [(t*B+b)][I] bf16   (transpose + cast)
// ---------------------------------------------------------------------------
__global__ void __launch_bounds__(256) k_transpose(
    const float* __restrict__ x, unsigned short* __restrict__ xs) {
  __shared__ float tile[64][65];
  const int b  = blockIdx.x;
  const int i0 = blockIdx.y * 64;
  const int t0 = blockIdx.z * 64;
  const int tid = threadIdx.x;
  const int c = tid & 63, r4 = tid >> 6;
  const float* src = x + (size_t)b * I_ * T_ + (size_t)i0 * T_ + t0;
#pragma unroll
  for (int it = 0; it < 16; ++it) {
    const int r = it * 4 + r4;
    tile[r][c] = src[(size_t)r * T_ + c];
  }
  __syncthreads();
#pragma unroll
  for (int it = 0; it < 16; ++it) {
    const int tr = it * 4 + r4;
    xs[((size_t)(t0 + tr) * B_ + b) * I_ + i0 + c] = f2bf(tile[c][tr]);
  }
}

// ---------------------------------------------------------------------------
// Kernel 2: persistent LSTM. 256 WGs x 256 thr (1 WG/CU, co-resident).
// WG(bt,jt): 32 batch rows x 16 h-units (x4 gates). K = 512(x) + 1024(h).
// Barrier: per-WG monotonic flag STORES (no RMW — R3's fetch_add serialized
// 256 same-line RMWs/step) + lane-parallel 64-flag poll by wave 0.
// h exchange: mode 1 = fresh buffer per step -> normal cached loads (L2-
// shared by the 32 same-bt WGs per XCD; reader XCD never saw the buffer
// before its producers wrote it, so no stale lines). mode 0 = R3 fallback
// (2 buffers + agent-scope L2-bypass loads) when ws_size is too small.
// ---------------------------------------------------------------------------
__global__ void __launch_bounds__(256, 1) k_lstm(
    const unsigned short* __restrict__ xs,    // [T*B][512] bf16
    const float* __restrict__ Whh,            // [4096][1024] fp32
    const float* __restrict__ Wih,            // [4096][512]  fp32
    const float* __restrict__ bih,            // [4096]
    const float* __restrict__ bhh,            // [4096]
    unsigned short* __restrict__ hbase,       // mode1: [256][128][1024] bf16
    float* __restrict__ out,                  // [128][1024] fp32
    unsigned int* __restrict__ flags,         // [256] zeroed, monotonic
    int mode)
{
  __shared__ unsigned short hst[2][32][264];  // staging, pitch 264 (528B)
  __shared__ float gx[4][32][17];             // gate exchange i/f/g/o

  const int wg = blockIdx.x, tid = threadIdx.x;
  const int lane = tid & 63, wave = tid >> 6; // wave == gate index q
  const int bt = wg & 3, jt = wg >> 2;        // jt in [0,64)
  const int b0 = bt * 32, j0 = jt * 16;
  const int quad = lane >> 4, cr = lane & 15;
  const size_t HBUF = (size_t)B_ * H_;        // 131072 shorts per h buffer

  // ---- preload weight B-fragments (static across all timesteps) ----
  short8 whf[32];                             // W_hh: K=1024
  {
    const float* wrow = Whh + (size_t)(wave * H_ + j0 + cr) * H_;
#pragma unroll
    for (int ks = 0; ks < 32; ++ks) {
      floatx4 wa = *(const floatx4*)(wrow + ks * 32 + quad * 8);
      floatx4 wb = *(const floatx4*)(wrow + ks * 32 + quad * 8 + 4);
      whf[ks] = pack_bf8(wa, wb);
    }
  }
  short8 wif[16];                             // W_ih: K=512
  {
    const float* irow = Wih + (size_t)(wave * H_ + j0 + cr) * I_;
#pragma unroll
    for (int ks = 0; ks < 16; ++ks) {
      floatx4 wa = *(const floatx4*)(irow + ks * 32 + quad * 8);
      floatx4 wb = *(const floatx4*)(irow + ks * 32 + quad * 8 + 4);
      wif[ks] = pack_bf8(wa, wb);
    }
  }

  const int eb = tid >> 3;    // epilogue batch row (0..31)
  const int ejp = tid & 7;    // epilogue j-pair   (0..7)
  float bias[4][2];
#pragma unroll
  for (int q = 0; q < 4; ++q)
#pragma unroll
    for (int jj = 0; jj < 2; ++jj)
      bias[q][jj] = bih[q * H_ + j0 + ejp * 2 + jj] + bhh[q * H_ + j0 + ejp * 2 + jj];

  const int srow = tid >> 3;  // staging row (0..31)
  const int sq = tid & 7;     // staging col octet

  float c0 = 0.f, c1 = 0.f;

  for (int t = 0; t < T_; ++t) {
    unsigned short* hout = hbase +
        (mode ? (size_t)t : (size_t)(1 - (t & 1))) * HBUF;
    const unsigned short* hin = hbase +
        (mode ? (size_t)(t > 0 ? t - 1 : 0) : (size_t)(t & 1)) * HBUF;
    const unsigned short* xrow = xs + ((size_t)t * B_ + b0 + srow) * I_ + sq * 8;
    const unsigned short* hrow = hin + (size_t)(b0 + srow) * H_ + sq * 8;

    // ---- x phase (no h dependence) ----
    {
      short8 s0 = *(const short8*)(xrow + 0);
      short8 s1 = *(const short8*)(xrow + 64);
      short8 s2 = *(const short8*)(xrow + 128);
      short8 s3 = *(const short8*)(xrow + 192);
      *(short8*)&hst[0][srow][sq * 8 + 0]   = s0;
      *(short8*)&hst[0][srow][sq * 8 + 64]  = s1;
      *(short8*)&hst[0][srow][sq * 8 + 128] = s2;
      *(short8*)&hst[0][srow][sq * 8 + 192] = s3;
    }
    __syncthreads();                                   // bar: x0 visible

    floatx4 accx0 = {0.f, 0.f, 0.f, 0.f};
    floatx4 accx1 = {0.f, 0.f, 0.f, 0.f};
    floatx4 acch0 = {0.f, 0.f, 0.f, 0.f};
    floatx4 acch1 = {0.f, 0.f, 0.f, 0.f};

    {
      short8 p0 = *(const short8*)(xrow + 256 + 0);
      short8 p1 = *(const short8*)(xrow + 256 + 64);
      short8 p2 = *(const short8*)(xrow + 256 + 128);
      short8 p3 = *(const short8*)(xrow + 256 + 192);
#pragma unroll
      for (int ks8 = 0; ks8 < 8; ++ks8) {
        short8 a0 = *(const short8*)&hst[0][cr][ks8 * 32 + quad * 8];
        short8 a1 = *(const short8*)&hst[0][16 + cr][ks8 * 32 + quad * 8];
        accx0 = __builtin_amdgcn_mfma_f32_16x16x32_bf16(a0, wif[ks8], accx0, 0, 0, 0);
        accx1 = __builtin_amdgcn_mfma_f32_16x16x32_bf16(a1, wif[ks8], accx1, 0, 0, 0);
      }
      *(short8*)&hst[1][srow][sq * 8 + 0]   = p0;
      *(short8*)&hst[1][srow][sq * 8 + 64]  = p1;
      *(short8*)&hst[1][srow][sq * 8 + 128] = p2;
      *(short8*)&hst[1][srow][sq * 8 + 192] = p3;
    }
    __syncthreads();                                   // bar: x1 visible

    // x chunk 1 MFMA (all waves; overlaps other WGs' publish latency)
#pragma unroll
    for (int ks8 = 0; ks8 < 8; ++ks8) {
      short8 a0 = *(const short8*)&hst[1][cr][ks8 * 32 + quad * 8];
      short8 a1 = *(const short8*)&hst[1][16 + cr][ks8 * 32 + quad * 8];
      accx0 = __builtin_amdgcn_mfma_f32_16x16x32_bf16(a0, wif[8 + ks8], accx0, 0, 0, 0);
      accx1 = __builtin_amdgcn_mfma_f32_16x16x32_bf16(a1, wif[8 + ks8], accx1, 0, 0, 0);
    }

    if (t > 0) {
      // ---- lane-parallel poll: wave 0 loads the 64 flags of group bt ----
      if (wave == 0) {
        const unsigned tgt = (unsigned)t;
        for (;;) {
          unsigned v = __hip_atomic_load(&flags[bt + 4 * lane], __ATOMIC_RELAXED,
                                         __HIP_MEMORY_SCOPE_AGENT);
          if (__ballot(v >= tgt) == ~0ull) break;
          __builtin_amdgcn_s_sleep(1);
        }
      }
      __syncthreads();                                 // bar: h(t) is readable

      // ---- load the 256B/thread h slice ----
      short8 hv8[16];
      if (mode) {
#pragma unroll
        for (int k = 0; k < 16; ++k)
          hv8[k] = *(const short8*)(hrow + (k >> 2) * 256 + (k & 3) * 64);
      } else {
#pragma unroll
        for (int k = 0; k < 16; ++k) {
          const unsigned short* p = hrow + (k >> 2) * 256 + (k & 3) * 64;
          union { unsigned long long u[2]; short8 v; } cvt;
          cvt.u[0] = __hip_atomic_load((const unsigned long long*)p,
                                       __ATOMIC_RELAXED, __HIP_MEMORY_SCOPE_AGENT);
          cvt.u[1] = __hip_atomic_load((const unsigned long long*)(p + 4),
                                       __ATOMIC_RELAXED, __HIP_MEMORY_SCOPE_AGENT);
          hv8[k] = cvt.v;
        }
      }

      // stage h chunk 0
#pragma unroll
      for (int p = 0; p < 4; ++p)
        *(short8*)&hst[0][srow][sq * 8 + p * 64] = hv8[p];
      __syncthreads();

      // h chunks 0..3 (K = 1024), double-buffered
#pragma unroll
      for (int ch = 0; ch < 4; ++ch) {
#pragma unroll
        for (int ks8 = 0; ks8 < 8; ++ks8) {
          short8 a0 = *(const short8*)&hst[ch & 1][cr][ks8 * 32 + quad * 8];
          short8 a1 = *(const short8*)&hst[ch & 1][16 + cr][ks8 * 32 + quad * 8];
          acch0 = __builtin_amdgcn_mfma_f32_16x16x32_bf16(a0, whf[ch * 8 + ks8], acch0, 0, 0, 0);
          acch1 = __builtin_amdgcn_mfma_f32_16x16x32_bf16(a1, whf[ch * 8 + ks8], acch1, 0, 0, 0);
        }
        if (ch < 3) {
#pragma unroll
          for (int p = 0; p < 4; ++p)
            *(short8*)&hst[(ch + 1) & 1][srow][sq * 8 + p * 64] = hv8[(ch + 1) * 4 + p];
          __syncthreads();
        }
      }
    }

    // ---- cross-wave gate exchange (gx is a distinct LDS array; the final
    // barrier of this step separates hst reads from next step's writes) ----
#pragma unroll
    for (int r = 0; r < 4; ++r) {
      gx[wave][quad * 4 + r][cr]      = accx0[r] + acch0[r];
      gx[wave][16 + quad * 4 + r][cr] = accx1[r] + acch1[r];
    }
    __syncthreads();                                   // bar: gx visible

    // ---- epilogue: activations, c update, h publish ----
    float hv0 = 0.f, hv1 = 0.f;
#pragma unroll
    for (int jj = 0; jj < 2; ++jj) {
      const int j = ejp * 2 + jj;
      float gi = gx[0][eb][j] + bias[0][jj];
      float gf = gx[1][eb][j] + bias[1][jj];
      float gg = gx[2][eb][j] + bias[2][jj];
      float go = gx[3][eb][j] + bias[3][jj];
      float si = 1.f / (1.f + __expf(-gi));
      float sf = 1.f / (1.f + __expf(-gf));
      float tg = 2.f / (1.f + __expf(-2.f * gg)) - 1.f;
      float so = 1.f / (1.f + __expf(-go));
      float& cc = jj ? c1 : c0;
      cc = sf * cc + si * tg;
      float th = 2.f / (1.f + __expf(-2.f * cc)) - 1.f;
      float hv = so * th;
      if (jj == 0) hv0 = hv; else hv1 = hv;
    }
    const unsigned hpack = (unsigned)f2bf(hv0) | ((unsigned)f2bf(hv1) << 16);
    // write-through to IF$ (coherence point)
    __hip_atomic_store((unsigned*)(hout + (size_t)(b0 + eb) * H_ + j0 + ejp * 2),
                       hpack, __ATOMIC_RELAXED, __HIP_MEMORY_SCOPE_AGENT);
    if (t == T_ - 1) {
      out[(size_t)(b0 + eb) * H_ + j0 + ejp * 2 + 0] = hv0;
      out[(size_t)(b0 + eb) * H_ + j0 + ejp * 2 + 1] = hv1;
    }

    // ---- publish: bar drains vmcnt(0) (h stores at IF$), then flag STORE ----
    __syncthreads();
    if (tid == 0)
      __hip_atomic_store(&flags[wg], (unsigned)(t + 1), __ATOMIC_RELAXED,
                         __HIP_MEMORY_SCOPE_AGENT);
  }
}

// ---------------------------------------------------------------------------
extern "C" void kernel_launch(void* const* d_in, const int* in_sizes, int n_in,
                              void* d_out, int out_size, void* d_ws, size_t ws_size,
                              hipStream_t stream) {
  (void)in_sizes; (void)n_in; (void)out_size;
  const float* x   = (const float*)d_in[0];
  const float* Wih = (const float*)d_in[1];
  const float* Whh = (const float*)d_in[2];
  const float* bih = (const float*)d_in[3];
  const float* bhh = (const float*)d_in[4];
  float* out = (float*)d_out;

  // layout: xs [0,33.5M) | flags [33.5M, +4K) | h buffers [33.56M, ...)
  char* ws = (char*)d_ws;
  unsigned short* xs = (unsigned short*)ws;                       // 33,554,432 B
  unsigned int*   fl = (unsigned int*)  (ws + 33554432);          //      4,096 B
  unsigned short* hb = (unsigned short*)(ws + 33558528);

  // mode 1 (per-step h buffers, cached loads) needs 256 x 262,144 B of h.
  const size_t need1 = 33558528ull + 256ull * 262144ull;          // ~100.7 MB
  const int mode = (ws_size >= need1) ? 1 : 0;

  hipMemsetAsync(fl, 0, 1024, stream);  // monotonic per-WG flags start at 0

  k_transpose<<<dim3(B_, I_ / 64, T_ / 64), 256, 0, stream>>>(x, xs);

  k_lstm<<<dim3(256), dim3(256), 0, stream>>>(xs, Whh, Wih, bih, bhh,
                                              hb, out, fl, mode);
}